// Round 9
// baseline (323.538 us; speedup 1.0000x reference)
//
#include <hip/hip_runtime.h>
#include <stdint.h>

#define N_ROWS 200000
#define NIMG   500
#define DMETA  24
#define WIDTH  32
#define HID    64
#define DEPTH  20
#define MC     32

// LDS: m-major, ONE [16][36]-f32 buffer per wave. Tiles AND stage-2 kf-halves
// time-multiplexed through it (per-wave DS ops are in-order -> WAR free).
// 5.1KB/block: tests whether block-residency was capping occupancy.
#define LSTRIDE_F 36
#define TILE_F    (16 * LSTRIDE_F)   // 576 floats = 2304 B per tile buffer

// ws layout (bytes): same as rounds 3/7/8.
#define WB    64000
#define LSTR  17920
#define OFF_WIH (WB + DEPTH * LSTR)      // 422400
#define OFF_WIL (OFF_WIH + 2048)
#define OFF_WSH (OFF_WIH + 4096)
#define OFF_WSL (OFF_WIH + 6144)         // end 430592 bytes of ws used

typedef __attribute__((ext_vector_type(8))) short bf16x8;
typedef __attribute__((ext_vector_type(4))) float f32x4;

#define MFMA(a, b, acc) __builtin_amdgcn_mfma_f32_16x16x32_bf16((a), (b), (acc), 0, 0, 0)

__device__ __forceinline__ uint32_t rotl32(uint32_t x, int r) {
    return (x << r) | (x >> (32 - r));
}

// JAX partitionable threefry, key (0,42): bits(j) = x0^x1 of threefry2x32((0,42),(0,j))
__device__ __forceinline__ uint32_t tf_bits(uint32_t j) {
    const uint32_t ks1 = 42u, ks2 = 0x1BD11BDAu ^ 42u;
    uint32_t x0 = 0u, x1 = j + ks1;
#define R4(a,b,c,d) \
    x0 += x1; x1 = rotl32(x1,(a)); x1 ^= x0; \
    x0 += x1; x1 = rotl32(x1,(b)); x1 ^= x0; \
    x0 += x1; x1 = rotl32(x1,(c)); x1 ^= x0; \
    x0 += x1; x1 = rotl32(x1,(d)); x1 ^= x0;
    R4(13,15,26,6)  x0 += ks1; x1 += ks2 + 1u;
    R4(17,29,16,24) x0 += ks2; x1 += 0u + 2u;
    R4(13,15,26,6)                x1 += ks1 + 3u;
    R4(17,29,16,24) x0 += ks1; x1 += ks2 + 4u;
    R4(13,15,26,6)  x0 += ks2; x1 += 0u + 5u;
#undef R4
    return x0 ^ x1;
}

__device__ __forceinline__ float bits_to_normal(uint32_t b) {
    float f = __uint_as_float((b >> 9) | 0x3f800000u) - 1.0f;
    const float lo = -0.99999994f;
    float u = fmaxf(lo, f * 2.0f + lo);
    return 1.41421356f * erfinvf(u);
}

// split (prep, scalar): round-half-up hi, truncated lo. |x - hi - lo| <~ 2^-16 |x|
__device__ __forceinline__ void split1(float x, short& hi, short& lo) {
    uint32_t b = __float_as_uint(x);
    uint32_t a = b + 0x8000u;
    hi = (short)(a >> 16);
    float r = x - __uint_as_float(a & 0xFFFF0000u);
    lo = (short)(__float_as_uint(r) >> 16);
}

// vector split+pack: 8 f32 -> bf16x8 hi, bf16x8 lo via v_cvt_pk_bf16_f32
__device__ __forceinline__ void split8p(const float* x, bf16x8& hi, bf16x8& lo) {
    uint32_t hu[4], lu[4];
#pragma unroll
    for (int p = 0; p < 4; ++p) {
        float x0 = x[2 * p], x1 = x[2 * p + 1];
        uint32_t h;
        asm("v_cvt_pk_bf16_f32 %0, %1, %2" : "=v"(h) : "v"(x0), "v"(x1));
        float r0 = x0 - __uint_as_float(h << 16);
        float r1 = x1 - __uint_as_float(h & 0xFFFF0000u);
        uint32_t l;
        asm("v_cvt_pk_bf16_f32 %0, %1, %2" : "=v"(l) : "v"(r0), "v"(r1));
        hu[p] = h;
        lu[p] = l;
    }
    __builtin_memcpy(&hi, hu, 16);
    __builtin_memcpy(&lo, lu, 16);
}

// single-precision pack: 8 f32 -> bf16x8 (RNE), 1 VALU per pair
__device__ __forceinline__ void cvt8p(const float* x, bf16x8& hi) {
    uint32_t hu[4];
#pragma unroll
    for (int p = 0; p < 4; ++p) {
        uint32_t h;
        asm("v_cvt_pk_bf16_f32 %0, %1, %2" : "=v"(h) : "v"(x[2 * p]), "v"(x[2 * p + 1]));
        hu[p] = h;
    }
    __builtin_memcpy(&hi, hu, 16);
}

// 20 residual blocks, two independent 16-row tiles per wave, one [16][36] LDS
// buffer time-multiplexed across {tile0,tile1} x {RT1, RT2-kf0, RT2-kf1}.
// Activations single RNE bf16 (A-operand), weights hi/lo (2 MFMA terms).
__device__ __forceinline__ void mlp20_x2(
    float* hC0, float* hC1, float* smw, const char* __restrict__ wsb,
    int lane, int q, int c) {
    const int ldsR = c * LSTRIDE_F + q * 8;       // read base (row m=c), dwords
    const int ldsW = q * 4 * LSTRIDE_F + c;       // write base (m=4q, k=c), dwords
    uint32_t offA  = (uint32_t)(WB + (lane << 4));    // stage1 t=0,1
    uint32_t offB  = offA + 4096u;                     // stage1 t=2,3
    uint32_t offC  = offA + 8192u;                     // stage2 kf=0
    uint32_t offD  = offA + 12288u;                    // stage2 kf=1
    uint32_t offB1 = (uint32_t)(WB + 16384 + (c << 4));
    uint32_t offB2 = (uint32_t)(WB + 17408 + (c << 4));
#pragma unroll 1
    for (int l = 0; l < DEPTH; ++l) {
        // RT1 tile0: h -> LDS -> A-frag (bf16)
        float a0[8], a1[8];
#pragma unroll
        for (int t = 0; t < 2; ++t)
#pragma unroll
            for (int r = 0; r < 4; ++r)
                smw[ldsW + r * LSTRIDE_F + t * 16] = hC0[t * 4 + r];
        {
            f32x4 v0 = *(const f32x4*)(smw + ldsR);
            f32x4 v1 = *(const f32x4*)(smw + ldsR + 4);
#pragma unroll
            for (int j = 0; j < 4; ++j) { a0[j] = v0[j]; a0[4 + j] = v1[j]; }
        }
        // RT1 tile1 (same buffer; per-wave DS in-order keeps WAR safe)
#pragma unroll
        for (int t = 0; t < 2; ++t)
#pragma unroll
            for (int r = 0; r < 4; ++r)
                smw[ldsW + r * LSTRIDE_F + t * 16] = hC1[t * 4 + r];
        {
            f32x4 u0 = *(const f32x4*)(smw + ldsR);
            f32x4 u1 = *(const f32x4*)(smw + ldsR + 4);
#pragma unroll
            for (int j = 0; j < 4; ++j) { a1[j] = u0[j]; a1[4 + j] = u1[j]; }
        }
        bf16x8 ah0, ah1;
        cvt8p(a0, ah0);
        cvt8p(a1, ah1);
        // stage 1: H1 = relu(h @ W1 + b1); bias quad is the MFMA C-operand
        float C1v0[16], C1v1[16];
#pragma unroll
        for (int t = 0; t < 4; ++t) {
            uint32_t o = (t < 2 ? offA : offB) + (uint32_t)((t & 1) << 11);
            bf16x8 bh = *(const bf16x8*)(wsb + o);
            bf16x8 bl = *(const bf16x8*)(wsb + o + 1024);
            f32x4 b1q = *(const f32x4*)(wsb + offB1 + (uint32_t)(t << 8));
            f32x4 acc = MFMA(ah0, bh, b1q);
            acc = MFMA(ah0, bl, acc);
            f32x4 acd = MFMA(ah1, bh, b1q);
            acd = MFMA(ah1, bl, acd);
#pragma unroll
            for (int r = 0; r < 4; ++r) {
                C1v0[t * 4 + r] = fmaxf(acc[r], 0.0f);
                C1v1[t * 4 + r] = fmaxf(acd[r], 0.0f);
            }
        }
        // RT2: H1 -> LDS -> A-frags, kf-halves time-muxed through the buffer
        bf16x8 xh0[2], xh1[2];
#pragma unroll
        for (int kf = 0; kf < 2; ++kf) {
#pragma unroll
            for (int t = 0; t < 2; ++t)
#pragma unroll
                for (int r = 0; r < 4; ++r)
                    smw[ldsW + r * LSTRIDE_F + t * 16] = C1v0[(kf * 2 + t) * 4 + r];
            f32x4 ea = *(const f32x4*)(smw + ldsR);
            f32x4 eb = *(const f32x4*)(smw + ldsR + 4);
            float e[8];
#pragma unroll
            for (int j = 0; j < 4; ++j) { e[j] = ea[j]; e[4 + j] = eb[j]; }
            cvt8p(e, xh0[kf]);
        }
#pragma unroll
        for (int kf = 0; kf < 2; ++kf) {
#pragma unroll
            for (int t = 0; t < 2; ++t)
#pragma unroll
                for (int r = 0; r < 4; ++r)
                    smw[ldsW + r * LSTRIDE_F + t * 16] = C1v1[(kf * 2 + t) * 4 + r];
            f32x4 ea = *(const f32x4*)(smw + ldsR);
            f32x4 eb = *(const f32x4*)(smw + ldsR + 4);
            float e[8];
#pragma unroll
            for (int j = 0; j < 4; ++j) { e[j] = ea[j]; e[4 + j] = eb[j]; }
            cvt8p(e, xh1[kf]);
        }
        // stage 2: h = h + H1 @ W2 + b2 ; residual + bias quad in acc init
        f32x4 b2q0 = *(const f32x4*)(wsb + offB2);
        f32x4 b2q1 = *(const f32x4*)(wsb + offB2 + 256u);
        f32x4 acc0[2], acc1[2];
#pragma unroll
        for (int r = 0; r < 4; ++r) {
            acc0[0][r] = hC0[r] + b2q0[r];
            acc0[1][r] = hC0[4 + r] + b2q1[r];
            acc1[0][r] = hC1[r] + b2q0[r];
            acc1[1][r] = hC1[4 + r] + b2q1[r];
        }
#pragma unroll
        for (int kf = 0; kf < 2; ++kf) {
#pragma unroll
            for (int t2 = 0; t2 < 2; ++t2) {
                uint32_t o = (kf ? offD : offC) + (uint32_t)(t2 << 11);
                bf16x8 bh = *(const bf16x8*)(wsb + o);
                bf16x8 bl = *(const bf16x8*)(wsb + o + 1024);
                acc0[t2] = MFMA(xh0[kf], bh, acc0[t2]);
                acc0[t2] = MFMA(xh0[kf], bl, acc0[t2]);
                acc1[t2] = MFMA(xh1[kf], bh, acc1[t2]);
                acc1[t2] = MFMA(xh1[kf], bl, acc1[t2]);
            }
        }
#pragma unroll
        for (int t2 = 0; t2 < 2; ++t2)
#pragma unroll
            for (int r = 0; r < 4; ++r) {
                hC0[t2 * 4 + r] = acc0[t2][r];
                hC1[t2 * 4 + r] = acc1[t2][r];
            }
        offA += LSTR; offB += LSTR; offC += LSTR; offD += LSTR;
        offB1 += LSTR; offB2 += LSTR;
    }
}

// input projection for one 16-row tile -> hC (C-layout); bias in acc init.
__device__ __forceinline__ void input_proj(
    const bf16x8& ah, const bf16x8& al, const short* __restrict__ wfh,
    const short* __restrict__ wfl, const float* __restrict__ bias,
    float* hC, int lane, int c) {
#pragma unroll
    for (int t = 0; t < 2; ++t) {
        bf16x8 bh = *(const bf16x8*)(wfh + ((t << 9) + (lane << 3)));
        bf16x8 bl = *(const bf16x8*)(wfl + ((t << 9) + (lane << 3)));
        float bb = bias[16 * t + c];
        f32x4 acc = {bb, bb, bb, bb};
        acc = MFMA(ah, bh, acc); acc = MFMA(ah, bl, acc); acc = MFMA(al, bh, acc);
#pragma unroll
        for (int r = 0; r < 4; ++r) hC[t * 4 + r] = acc[r];
    }
}

// prep: zero sums; per-layer weight blocks + broadcast bias quads; wimg/wscale.
__global__ __launch_bounds__(256) void prep_kernel(
    const float* __restrict__ w1, const float* __restrict__ w2,
    const float* __restrict__ wimg, const float* __restrict__ wsc,
    const float* __restrict__ b1, const float* __restrict__ b2,
    char* __restrict__ wsb) {
    int t = blockIdx.x * 256 + threadIdx.x;
    float* sums = (float*)wsb;
    if (t < 16000) { sums[t] = 0.0f; return; }
    t -= 16000;
    if (t < 40960) {  // stage1 frags: [l][t][lane][j]
        int l = t >> 11, r = t & 2047, tt = r >> 9, r2 = r & 511;
        int lane = r2 >> 3, j = r2 & 7;
        int k = (lane >> 4) * 8 + j, n = 16 * tt + (lane & 15);
        short h, lo;
        split1(w1[l * 2048 + k * 64 + n], h, lo);
        char* base = wsb + WB + l * LSTR + tt * 2048 + 2 * r2;
        *(short*)(base) = h;
        *(short*)(base + 1024) = lo;
        return;
    }
    t -= 40960;
    if (t < 40960) {  // stage2 frags: [l][kf][t2][lane][j]
        int l = t >> 11, r = t & 2047, kf = r >> 10, r2 = r & 1023;
        int t2 = r2 >> 9, r3 = r2 & 511, lane = r3 >> 3, j = r3 & 7;
        int k = kf * 32 + (lane >> 4) * 8 + j, n = 16 * t2 + (lane & 15);
        short h, lo;
        split1(w2[l * 2048 + k * 32 + n], h, lo);
        char* base = wsb + WB + l * LSTR + 8192 + (kf * 2 + t2) * 2048 + 2 * r3;
        *(short*)(base) = h;
        *(short*)(base + 1024) = lo;
        return;
    }
    t -= 40960;
    if (t < 1024) {  // wimg frags (K padded 26->32)
        int tt = t >> 9, r = t & 511, lane = r >> 3, j = r & 7;
        int k = (lane >> 4) * 8 + j, n = 16 * tt + (lane & 15);
        float v = (k < 26) ? wimg[k * 32 + n] : 0.0f;
        short h, lo;
        split1(v, h, lo);
        ((short*)(wsb + OFF_WIH))[t] = h;
        ((short*)(wsb + OFF_WIL))[t] = lo;
        return;
    }
    t -= 1024;
    if (t < 1024) {  // wscale frags (K padded 24->32)
        int tt = t >> 9, r = t & 511, lane = r >> 3, j = r & 7;
        int k = (lane >> 4) * 8 + j, n = 16 * tt + (lane & 15);
        float v = (k < 24) ? wsc[k * 32 + n] : 0.0f;
        short h, lo;
        split1(v, h, lo);
        ((short*)(wsb + OFF_WSH))[t] = h;
        ((short*)(wsb + OFF_WSL))[t] = lo;
        return;
    }
    t -= 1024;
    if (t < 5120) {  // bias1 quads: [l][t(4)][c(16)] x4 floats, bcast b1[l][16t+c]
        int l = t >> 8, r = t & 255;
        int tt = r >> 6, cc = (r >> 2) & 15;
        *(float*)(wsb + WB + l * LSTR + 16384 + 4 * r) = b1[l * 64 + tt * 16 + cc];
        return;
    }
    t -= 5120;
    if (t < 2560) {  // bias2 quads: [l][t2(2)][c(16)] x4 floats, bcast b2[l][16t2+c]
        int l = t >> 7, r = t & 127;
        int t2 = r >> 6, cc = (r >> 2) & 15;
        *(float*)(wsb + WB + l * LSTR + 17408 + 4 * r) = b2[l * 32 + t2 * 16 + cc];
        return;
    }
}

// load A-frag of X[16,32] for rows base..base+15 (cols: 24 md, iobs, sig, pad)
__device__ __forceinline__ void load_xfrag(
    const float* __restrict__ md, const float* __restrict__ iobs,
    const float* __restrict__ sig, int base, int q, int c,
    bf16x8& ah, bf16x8& al) {
    float xa[8];
    if (q < 3) {
        const f32x4* rp = (const f32x4*)(md + (size_t)(base + c) * DMETA + q * 8);
        f32x4 v0 = rp[0], v1 = rp[1];
#pragma unroll
        for (int j = 0; j < 4; ++j) { xa[j] = v0[j]; xa[4 + j] = v1[j]; }
    } else {
        xa[0] = iobs ? iobs[base + c] : 0.0f;
        xa[1] = sig ? sig[base + c] : 0.0f;
#pragma unroll
        for (int j = 2; j < 8; ++j) xa[j] = 0.0f;
    }
    split8p(xa, ah, al);
}

// pass A: input proj -> mlp20 (2 tiles/wave) -> segment-sum (uniform-id fast path)
__global__ __launch_bounds__(128, 4) void pass_a(
    const float* __restrict__ md, const float* __restrict__ iobs,
    const float* __restrict__ sig, const float* __restrict__ bimg,
    const char* __restrict__ wsb, const int* __restrict__ ids,
    float* __restrict__ sums) {
    __shared__ __attribute__((aligned(16))) float smat[2][TILE_F];
    int lane = threadIdx.x & 63, w = threadIdx.x >> 6;
    int q = lane >> 4, c = lane & 15;
    int i0 = (blockIdx.x * 2 + w) * 32;
    float* smw = &smat[w][0];

    bf16x8 ah0, al0, ah1, al1;
    load_xfrag(md, iobs, sig, i0, q, c, ah0, al0);
    load_xfrag(md, iobs, sig, i0 + 16, q, c, ah1, al1);

    float hC0[8], hC1[8];
    input_proj(ah0, al0, (const short*)(wsb + OFF_WIH), (const short*)(wsb + OFF_WIL),
               bimg, hC0, lane, c);
    input_proj(ah1, al1, (const short*)(wsb + OFF_WIH), (const short*)(wsb + OFF_WIL),
               bimg, hC1, lane, c);

    mlp20_x2(hC0, hC1, smw, wsb, lane, q, c);

#pragma unroll
    for (int tile = 0; tile < 2; ++tile) {
        const float* hC = tile ? hC1 : hC0;
        int tb = i0 + tile * 16;
        bool uni = (ids[tb] == ids[tb + 15]);   // wave-uniform branch
        if (uni) {
            int id = ids[tb];
#pragma unroll
            for (int t = 0; t < 2; ++t) {
                float s = (hC[t * 4 + 0] + hC[t * 4 + 1]) + (hC[t * 4 + 2] + hC[t * 4 + 3]);
                s += __shfl_xor(s, 16, 64);
                s += __shfl_xor(s, 32, 64);
                if (q == 0) atomicAdd(&sums[id * 32 + 16 * t + c], s);
            }
        } else {
            int idv[4];
#pragma unroll
            for (int r = 0; r < 4; ++r) idv[r] = ids[tb + q * 4 + r];
#pragma unroll
            for (int t = 0; t < 2; ++t)
#pragma unroll
                for (int r = 0; r < 4; ++r)
                    atomicAdd(&sums[idv[r] * 32 + 16 * t + c], hC[t * 4 + r]);
        }
    }
}

__global__ __launch_bounds__(256) void normalize_kernel(float* __restrict__ sums,
                                                        const int* __restrict__ cnts) {
    int t = blockIdx.x * 256 + threadIdx.x;
    if (t < NIMG * WIDTH) {
        int img = t >> 5;
        float cc = (float)max(cnts[img], 1);
        sums[t] = sums[t] / cc;
    }
}

// pass B: input proj + pooled -> mlp20 (2 tiles/wave) -> head -> sample -> z, kl
__global__ __launch_bounds__(128, 4) void pass_b(
    const float* __restrict__ md, const float* __restrict__ bsc,
    const char* __restrict__ wsb, const float* __restrict__ wout,
    const float* __restrict__ bout, const int* __restrict__ ids,
    const float* __restrict__ pooled, float* __restrict__ out) {
    __shared__ __attribute__((aligned(16))) float smat[2][TILE_F];
    __shared__ float sls[2][64];
    int lane = threadIdx.x & 63, w = threadIdx.x >> 6;
    int q = lane >> 4, c = lane & 15;
    int i0 = (blockIdx.x * 2 + w) * 32;
    float* smw = &smat[w][0];

    bf16x8 ah0, al0, ah1, al1;
    load_xfrag(md, nullptr, nullptr, i0, q, c, ah0, al0);
    load_xfrag(md, nullptr, nullptr, i0 + 16, q, c, ah1, al1);

    float hC0[8], hC1[8];
    input_proj(ah0, al0, (const short*)(wsb + OFF_WSH), (const short*)(wsb + OFF_WSL),
               bsc, hC0, lane, c);
    input_proj(ah1, al1, (const short*)(wsb + OFF_WSH), (const short*)(wsb + OFF_WSL),
               bsc, hC1, lane, c);
    // add pooled[id] per row
#pragma unroll
    for (int tile = 0; tile < 2; ++tile) {
        float* hC = tile ? hC1 : hC0;
        int tb = i0 + tile * 16;
        int idv[4];
#pragma unroll
        for (int r = 0; r < 4; ++r) idv[r] = ids[tb + q * 4 + r];
#pragma unroll
        for (int t = 0; t < 2; ++t)
#pragma unroll
            for (int r = 0; r < 4; ++r)
                hC[t * 4 + r] += pooled[idv[r] * 32 + 16 * t + c];
    }

    mlp20_x2(hC0, hC1, smw, wsb, lane, q, c);

    // head per tile: params = h @ wout + bout (reduce across the 16 c-lanes)
    float wo0[2], wo1[2];
#pragma unroll
    for (int t = 0; t < 2; ++t) {
        float2 wv = ((const float2*)wout)[16 * t + c];
        wo0[t] = wv.x; wo1[t] = wv.y;
    }
#pragma unroll
    for (int tile = 0; tile < 2; ++tile) {
        const float* hC = tile ? hC1 : hC0;
        float p0r[4], p1r[4];
#pragma unroll
        for (int r = 0; r < 4; ++r) {
            p0r[r] = hC[r] * wo0[0] + hC[4 + r] * wo0[1];
            p1r[r] = hC[r] * wo1[0] + hC[4 + r] * wo1[1];
        }
#pragma unroll
        for (int m = 1; m < 16; m <<= 1) {
#pragma unroll
            for (int r = 0; r < 4; ++r) {
                p0r[r] += __shfl_xor(p0r[r], m, 64);
                p1r[r] += __shfl_xor(p1r[r], m, 64);
            }
        }
        if (c == 0) {
#pragma unroll
            for (int r = 0; r < 4; ++r) {
                float loc = p0r[r] + bout[0];
                float pb = p1r[r] + bout[1];
                float scale = fmaxf(pb, 0.0f) + log1pf(expf(-fabsf(pb))) + 1e-12f;
                sls[w][tile * 16 + q * 4 + r] = loc;
                sls[w][32 + tile * 16 + q * 4 + r] = scale;
            }
        }
    }

    // sampling: lane covers row (i0 + lane&31), draws half*16..+15
    int ro = lane & 31, half = lane >> 5;
    int row = i0 + ro;
    float L = sls[w][ro];
    float S = sls[w][32 + ro];
    float lsg = logf(S);
    float kp = 0.0f;
    float* zrow = out + (size_t)row * MC + half * 16;
#pragma unroll 4
    for (int s4 = 0; s4 < 4; ++s4) {
        f32x4 zv;
#pragma unroll
        for (int jj = 0; jj < 4; ++jj) {
            int t = half * 16 + s4 * 4 + jj;
            uint32_t j = (uint32_t)(t * N_ROWS) + (uint32_t)row;
            float n = bits_to_normal(tf_bits(j));
            float z = fmaf(S, n, L);
            zv[jj] = z;
            kp += fmaf(-0.5f, n * n, fabsf(z));
        }
        *(f32x4*)(zrow + s4 * 4) = zv;
    }
    kp += __shfl_xor(kp, 32, 64);
    if (half == 0) {
        out[(size_t)N_ROWS * MC + row] =
            0.01f * (kp * (1.0f / 32.0f) - lsg - 0.91893853320467274f + 0.69314718055994531f);
    }
}

extern "C" void kernel_launch(void* const* d_in, const int* in_sizes, int n_in,
                              void* d_out, int out_size, void* d_ws, size_t ws_size,
                              hipStream_t stream) {
    const float* md   = (const float*)d_in[0];
    const float* iobs = (const float*)d_in[1];
    const float* sig  = (const float*)d_in[2];
    const float* wimg = (const float*)d_in[3];
    const float* bimg = (const float*)d_in[4];
    const float* wsc  = (const float*)d_in[5];
    const float* bsc  = (const float*)d_in[6];
    const float* w1   = (const float*)d_in[7];
    const float* b1   = (const float*)d_in[8];
    const float* w2   = (const float*)d_in[9];
    const float* b2   = (const float*)d_in[10];
    const float* wout = (const float*)d_in[11];
    const float* bout = (const float*)d_in[12];
    const int* ids    = (const int*)d_in[13];
    const int* cnts   = (const int*)d_in[14];
    float* out = (float*)d_out;
    char* wsb = (char*)d_ws;
    float* sums = (float*)wsb;

    const int nblk = N_ROWS / 64;  // 3125 blocks x 2 waves x 32 rows, exact
    prep_kernel<<<421, 256, 0, stream>>>(w1, w2, wimg, wsc, b1, b2, wsb);
    pass_a<<<nblk, 128, 0, stream>>>(md, iobs, sig, bimg, wsb, ids, sums);
    normalize_kernel<<<(NIMG * WIDTH + 255) / 256, 256, 0, stream>>>(sums, cnts);
    pass_b<<<nblk, 128, 0, stream>>>(md, bsc, wsb, wout, bout, ids, sums, out);
}